// Round 17
// baseline (567.501 us; speedup 1.0000x reference)
//
#include <hip/hip_runtime.h>
#include <hip/hip_bf16.h>

using short8  = __attribute__((ext_vector_type(8))) short;
using float4v = __attribute__((ext_vector_type(4))) float;

__device__ __forceinline__ float4 f4zero() { return make_float4(0.f, 0.f, 0.f, 0.f); }

__device__ __forceinline__ float bfhi2f(unsigned short u) {
    return __uint_as_float(((unsigned int)u) << 16);
}
__device__ __forceinline__ unsigned short f2bf_rn(float x) {
    unsigned int u = __float_as_uint(x);
    u += 0x7FFFu + ((u >> 16) & 1u);
    return (unsigned short)(u >> 16);
}
__device__ __forceinline__ void split_bf(float v, unsigned short& h, unsigned short& l) {
    h = f2bf_rn(v);
    l = f2bf_rn(v - bfhi2f(h));
}
// packed pair convert: dst.lo16 = bf16(a), dst.hi16 = bf16(b) — single VALU op
__device__ __forceinline__ unsigned cvt_pk_bf16(float a, float b) {
    unsigned r;
    asm("v_cvt_pk_bf16_f32 %0, %1, %2" : "=v"(r) : "v"(a), "v"(b));
    return r;
}
// hi/lo split of a pair. Self-correcting: lo = x - hi exactly compensates hi rounding.
__device__ __forceinline__ void split_pk(float x, float y, unsigned& hp, unsigned& lp) {
    hp = cvt_pk_bf16(x, y);
    const float hx = __uint_as_float(hp << 16);
    const float hy = __uint_as_float(hp & 0xFFFF0000u);
    lp = cvt_pk_bf16(x - hx, y - hy);
}
__device__ __forceinline__ short8 ld_s8(const unsigned short* p) {   // 16B-aligned
    return *(const short8*)p;
}
union U8 { short8 s; uint4 u; };

// ---------------- weight prep ----------------
__global__ __launch_bounds__(256) void tsplit_pair_kernel(
    const float* __restrict__ W0, int K0, const float* __restrict__ W1, int K1,
    unsigned short* __restrict__ oh, unsigned short* __restrict__ ol)
{
    const int m = blockIdx.x >> 4;
    const int idx = (blockIdx.x & 15) * 256 + threadIdx.x;   // 0..4095
    const int n = idx >> 5, k = idx & 31;
    const float* W = m ? W1 : W0;
    const int K = m ? K1 : K0;
    const float v = (k < K) ? W[(size_t)k * 128 + n] : 0.f;
    unsigned short h, l;
    split_bf(v, h, l);
    oh[m * 4096 + idx] = h; ol[m * 4096 + idx] = l;
}

struct SrcList8 { const float* p[8]; };
__global__ __launch_bounds__(256) void tsplit8_kernel(
    SrcList8 src, unsigned short* __restrict__ dh, unsigned short* __restrict__ dl)
{
    const int m = blockIdx.x >> 6;
    const int idx = (blockIdx.x & 63) * 256 + threadIdx.x;  // 0..16383
    const int n = idx >> 7, k = idx & 127;
    const float v = src.p[m][(size_t)k * 128 + n];
    unsigned short h, l;
    split_bf(v, h, l);
    dh[m * 16384 + idx] = h; dl[m * 16384 + idx] = l;
}

struct SrcList2 { const float* p[2]; };
__global__ __launch_bounds__(256) void tsplit2_kernel(
    SrcList2 src, unsigned short* __restrict__ dh, unsigned short* __restrict__ dl)
{
    const int m = blockIdx.x >> 7;
    const int idx = (blockIdx.x & 127) * 256 + threadIdx.x; // 0..32767
    const int n = idx >> 8, k = idx & 255;
    const float v = src.p[m][(size_t)k * 128 + n];
    unsigned short h, l;
    split_bf(v, h, l);
    dh[m * 32768 + idx] = h; dl[m * 32768 + idx] = l;
}

// ---------------- sort pipeline ----------------
__global__ __launch_bounds__(256) void hist_kernel(
    const int* __restrict__ ei, int* __restrict__ cnt, int E)
{
    const int i = blockIdx.x * blockDim.x + threadIdx.x;
    if (i < E) atomicAdd(&cnt[ei[E + i]], 1);
}

__global__ __launch_bounds__(256) void scan_kernel(
    const int* __restrict__ cnt, int* __restrict__ fill, int n)
{
    __shared__ int part[256];
    const int tid = threadIdx.x;
    const int chunk = (n + 255) / 256;
    const int beg = tid * chunk;
    const int end = min(beg + chunk, n);
    int s = 0;
    for (int i = beg; i < end; ++i) s += cnt[i];
    part[tid] = s;
    __syncthreads();
    for (int off = 1; off < 256; off <<= 1) {
        const int v = (tid >= off) ? part[tid - off] : 0;
        __syncthreads();
        part[tid] += v;
        __syncthreads();
    }
    int prefix = (tid == 0) ? 0 : part[tid - 1];
    for (int i = beg; i < end; ++i) { fill[i] = prefix; prefix += cnt[i]; }
}

// scatter fused with edge-feat permute+split (R10 proven)
__global__ __launch_bounds__(256) void scatter_kernel(
    const int* __restrict__ ei, const float* __restrict__ ef,
    int* __restrict__ fill, int* __restrict__ ssrc, int* __restrict__ sdst,
    unsigned short* __restrict__ efh, unsigned short* __restrict__ efl, int E)
{
    const int e = blockIdx.x * blockDim.x + threadIdx.x;
    if (e < E) {
        const int d = ei[E + e];
        const int pos = atomicAdd(&fill[d], 1);
        ssrc[pos] = ei[e];
        sdst[pos] = d;
        const float4 v0 = *(const float4*)&ef[(size_t)e * 16];
        const float4 v1 = *(const float4*)&ef[(size_t)e * 16 + 4];
        const float4 v2 = *(const float4*)&ef[(size_t)e * 16 + 8];
        const float4 v3 = *(const float4*)&ef[(size_t)e * 16 + 12];
        U8 H0, L0, H1, L1;
        unsigned h, lo2;
        split_pk(v0.x, v0.y, h, lo2); H0.u.x = h; L0.u.x = lo2;
        split_pk(v0.z, v0.w, h, lo2); H0.u.y = h; L0.u.y = lo2;
        split_pk(v1.x, v1.y, h, lo2); H0.u.z = h; L0.u.z = lo2;
        split_pk(v1.z, v1.w, h, lo2); H0.u.w = h; L0.u.w = lo2;
        split_pk(v2.x, v2.y, h, lo2); H1.u.x = h; L1.u.x = lo2;
        split_pk(v2.z, v2.w, h, lo2); H1.u.y = h; L1.u.y = lo2;
        split_pk(v3.x, v3.y, h, lo2); H1.u.z = h; L1.u.z = lo2;
        split_pk(v3.z, v3.w, h, lo2); H1.u.w = h; L1.u.w = lo2;
        *(uint4*)&efh[(size_t)pos * 16]     = H0.u;
        *(uint4*)&efh[(size_t)pos * 16 + 8] = H1.u;
        *(uint4*)&efl[(size_t)pos * 16]     = L0.u;
        *(uint4*)&efl[(size_t)pos * 16 + 8] = L1.u;
    }
}

// =====================================================================
// Fused node kernels — 64-row tiles, 256 threads (R14 fused projection)
// =====================================================================
__device__ __forceinline__ void node_epilogue_proj(
    float4v (&acc)[4][2], unsigned short* ahi, unsigned short* alo,
    const float* bias, const unsigned short* v1h, const unsigned short* v1l,
    const unsigned short* v2h, const unsigned short* v2l,
    float* C, float* P1, float* P2,
    int r0, int M, int w, int quad, int l16)
{
    __syncthreads();
#pragma unroll
    for (int t = 0; t < 2; ++t) {
        const int col = (2 * w + t) * 16 + l16;
        const float bcol = bias[col];
#pragma unroll
        for (int mt = 0; mt < 4; ++mt) {
            float c[4];
#pragma unroll
            for (int r = 0; r < 4; ++r) {
                const int row = mt * 16 + quad * 4 + r;
                c[r] = fmaxf(acc[mt][t][r] + bcol, 0.f);
                if (r0 + row < M) C[(size_t)(r0 + row) * 128 + col] = c[r];
            }
            unsigned hp01, lp01, hp23, lp23;
            split_pk(c[0], c[1], hp01, lp01);
            split_pk(c[2], c[3], hp23, lp23);
            const int rb = (mt * 16 + quad * 4) * 136 + col;
            ahi[rb]       = (unsigned short)hp01;         alo[rb]       = (unsigned short)lp01;
            ahi[rb + 136] = (unsigned short)(hp01 >> 16); alo[rb + 136] = (unsigned short)(lp01 >> 16);
            ahi[rb + 272] = (unsigned short)hp23;         alo[rb + 272] = (unsigned short)lp23;
            ahi[rb + 408] = (unsigned short)(hp23 >> 16); alo[rb + 408] = (unsigned short)(lp23 >> 16);
        }
    }
    __syncthreads();

    // fused dual projection: one pass over c4/mt, A-frags read once
    float4v pa[4][2], pb[4][2];
#pragma unroll
    for (int mt = 0; mt < 4; ++mt)
#pragma unroll
        for (int t = 0; t < 2; ++t) { pa[mt][t] = (float4v)0.f; pb[mt][t] = (float4v)0.f; }
#pragma unroll
    for (int c4 = 0; c4 < 4; ++c4) {
        const int k0 = c4 * 32;
        short8 b1h[2], b1l[2], b2h[2], b2l[2];
#pragma unroll
        for (int t = 0; t < 2; ++t) {
            const int g = ((2 * w + t) * 16 + l16) * 128 + k0 + quad * 8;
            b1h[t] = ld_s8(&v1h[g]);
            b1l[t] = ld_s8(&v1l[g]);
            b2h[t] = ld_s8(&v2h[g]);
            b2l[t] = ld_s8(&v2l[g]);
        }
#pragma unroll
        for (int mt = 0; mt < 4; ++mt) {
            const int base = (mt * 16 + l16) * 136 + k0 + quad * 8;
            const short8 ah = ld_s8(&ahi[base]);
            const short8 al = ld_s8(&alo[base]);
#pragma unroll
            for (int t = 0; t < 2; ++t) {
                pa[mt][t] = __builtin_amdgcn_mfma_f32_16x16x32_bf16(ah, b1h[t], pa[mt][t], 0, 0, 0);
                pa[mt][t] = __builtin_amdgcn_mfma_f32_16x16x32_bf16(ah, b1l[t], pa[mt][t], 0, 0, 0);
                pa[mt][t] = __builtin_amdgcn_mfma_f32_16x16x32_bf16(al, b1h[t], pa[mt][t], 0, 0, 0);
                pb[mt][t] = __builtin_amdgcn_mfma_f32_16x16x32_bf16(ah, b2h[t], pb[mt][t], 0, 0, 0);
                pb[mt][t] = __builtin_amdgcn_mfma_f32_16x16x32_bf16(ah, b2l[t], pb[mt][t], 0, 0, 0);
                pb[mt][t] = __builtin_amdgcn_mfma_f32_16x16x32_bf16(al, b2h[t], pb[mt][t], 0, 0, 0);
            }
        }
    }
#pragma unroll
    for (int t = 0; t < 2; ++t) {
        const int col = (2 * w + t) * 16 + l16;
#pragma unroll
        for (int mt = 0; mt < 4; ++mt)
#pragma unroll
            for (int r = 0; r < 4; ++r) {
                const int row = mt * 16 + quad * 4 + r;
                if (r0 + row < M) {
                    P1[(size_t)(r0 + row) * 128 + col] = pa[mt][t][r];
                    P2[(size_t)(r0 + row) * 128 + col] = pb[mt][t][r];
                }
            }
    }
}

__global__ __launch_bounds__(256) void encode_mfma_kernel(
    const float* __restrict__ X,
    const unsigned short* __restrict__ wTh, const unsigned short* __restrict__ wTl,
    const float* __restrict__ bias,
    const unsigned short* __restrict__ v1h, const unsigned short* __restrict__ v1l,
    const unsigned short* __restrict__ v2h, const unsigned short* __restrict__ v2l,
    float* __restrict__ C, float* __restrict__ P1, float* __restrict__ P2, int M)
{
    __shared__ __align__(16) char smem[34816];
    unsigned short* ahi = (unsigned short*)smem;
    unsigned short* alo = (unsigned short*)(smem + 17408);
    const int tid = threadIdx.x;
    const int w = tid >> 6, l = tid & 63, quad = l >> 4, l16 = l & 15;
    const int r0 = blockIdx.x * 64;

#pragma unroll
    for (int rep = 0; rep < 2; ++rep) {
        const int fid = tid + rep * 256;
        const int row = fid >> 3, kq = fid & 7;
        float4 v = f4zero();
        if (r0 + row < M) v = *(const float4*)&X[(size_t)(r0 + row) * 32 + 4 * kq];
        unsigned hpx, lpx, hpy, lpy;
        split_pk(v.x, v.y, hpx, lpx);
        split_pk(v.z, v.w, hpy, lpy);
        uint2 hp; hp.x = hpx; hp.y = hpy;
        uint2 lp; lp.x = lpx; lp.y = lpy;
        *(uint2*)&ahi[row * 136 + 4 * kq] = hp;
        *(uint2*)&alo[row * 136 + 4 * kq] = lp;
    }
    __syncthreads();

    float4v acc[4][2];
#pragma unroll
    for (int mt = 0; mt < 4; ++mt)
#pragma unroll
        for (int t = 0; t < 2; ++t) acc[mt][t] = (float4v)0.f;

    {
        short8 bh[2], bl[2];
#pragma unroll
        for (int t = 0; t < 2; ++t) {
            const int g = ((2 * w + t) * 16 + l16) * 32 + quad * 8;
            bh[t] = ld_s8(&wTh[g]);
            bl[t] = ld_s8(&wTl[g]);
        }
#pragma unroll
        for (int mt = 0; mt < 4; ++mt) {
            const int base = (mt * 16 + l16) * 136 + quad * 8;
            const short8 ah = ld_s8(&ahi[base]);
            const short8 al = ld_s8(&alo[base]);
#pragma unroll
            for (int t = 0; t < 2; ++t) {
                acc[mt][t] = __builtin_amdgcn_mfma_f32_16x16x32_bf16(ah, bh[t], acc[mt][t], 0, 0, 0);
                acc[mt][t] = __builtin_amdgcn_mfma_f32_16x16x32_bf16(ah, bl[t], acc[mt][t], 0, 0, 0);
                acc[mt][t] = __builtin_amdgcn_mfma_f32_16x16x32_bf16(al, bh[t], acc[mt][t], 0, 0, 0);
            }
        }
    }
    node_epilogue_proj(acc, ahi, alo, bias, v1h, v1l, v2h, v2l, C, P1, P2, r0, M, w, quad, l16);
}

__global__ __launch_bounds__(256) void update_mfma_kernel(
    const float* __restrict__ A1, float* __restrict__ A2,
    const unsigned short* __restrict__ wTh, const unsigned short* __restrict__ wTl,
    const float* __restrict__ bias,
    const unsigned short* __restrict__ v1h, const unsigned short* __restrict__ v1l,
    const unsigned short* __restrict__ v2h, const unsigned short* __restrict__ v2l,
    float* __restrict__ C, float* __restrict__ P1, float* __restrict__ P2, int M)
{
    __shared__ __align__(16) char smem[34816];
    unsigned short* ahi = (unsigned short*)smem;
    unsigned short* alo = (unsigned short*)(smem + 17408);
    const int tid = threadIdx.x;
    const int w = tid >> 6, l = tid & 63, quad = l >> 4, l16 = l & 15;
    const int r0 = blockIdx.x * 64;

    float4v acc[4][2];
#pragma unroll
    for (int mt = 0; mt < 4; ++mt)
#pragma unroll
        for (int t = 0; t < 2; ++t) acc[mt][t] = (float4v)0.f;

    for (int half = 0; half < 2; ++half) {
        const float* A = half ? A2 : A1;
        if (half) __syncthreads();
#pragma unroll
        for (int rep = 0; rep < 8; ++rep) {
            const int fid = tid + rep * 256;
            const int row = fid >> 5, kq = fid & 31;
            float4 v = f4zero();
            if (r0 + row < M) v = *(const float4*)&A[(size_t)(r0 + row) * 128 + 4 * kq];
            unsigned hpx, lpx, hpy, lpy;
            split_pk(v.x, v.y, hpx, lpx);
            split_pk(v.z, v.w, hpy, lpy);
            uint2 hp; hp.x = hpx; hp.y = hpy;
            uint2 lp; lp.x = lpx; lp.y = lpy;
            *(uint2*)&ahi[row * 136 + 4 * kq] = hp;
            *(uint2*)&alo[row * 136 + 4 * kq] = lp;
            // zero the agg buffer as a side effect (after v is consumed)
            if (half == 1 && r0 + row < M)
                *(float4*)&A2[(size_t)(r0 + row) * 128 + 4 * kq] = f4zero();
        }
        __syncthreads();
#pragma unroll
        for (int c4 = 0; c4 < 4; ++c4) {
            const int k0 = c4 * 32;
            short8 bh[2], bl[2];
#pragma unroll
            for (int t = 0; t < 2; ++t) {
                const int g = ((2 * w + t) * 16 + l16) * 256 + half * 128 + k0 + quad * 8;
                bh[t] = ld_s8(&wTh[g]);
                bl[t] = ld_s8(&wTl[g]);
            }
#pragma unroll
            for (int mt = 0; mt < 4; ++mt) {
                const int base = (mt * 16 + l16) * 136 + k0 + quad * 8;
                const short8 ah = ld_s8(&ahi[base]);
                const short8 al = ld_s8(&alo[base]);
#pragma unroll
                for (int t = 0; t < 2; ++t) {
                    acc[mt][t] = __builtin_amdgcn_mfma_f32_16x16x32_bf16(ah, bh[t], acc[mt][t], 0, 0, 0);
                    acc[mt][t] = __builtin_amdgcn_mfma_f32_16x16x32_bf16(ah, bl[t], acc[mt][t], 0, 0, 0);
                    acc[mt][t] = __builtin_amdgcn_mfma_f32_16x16x32_bf16(al, bh[t], acc[mt][t], 0, 0, 0);
                }
            }
        }
    }
    node_epilogue_proj(acc, ahi, alo, bias, v1h, v1l, v2h, v2l, C, P1, P2, r0, M, w, quad, l16);
}

// ---- fused edge path: 64-edge tiles, 512 threads (8 waves x 16 cols) ----
// R16 form (measured best ~136.0 µs): pinned mid-weight hoist + hoisted
// reduce gathers + lgkm-only spill barrier + scalarized reduce. Unchanged.
__global__ __launch_bounds__(512, 8) void edge_msg_mfma_kernel(
    const unsigned short* __restrict__ efh, const unsigned short* __restrict__ efl,
    const int* __restrict__ ssrc, const int* __restrict__ sdst,
    const unsigned short* __restrict__ wehT_h, const unsigned short* __restrict__ wehT_l,
    const float* __restrict__ be,
    const unsigned short* __restrict__ wmT_h, const unsigned short* __restrict__ wmT_l,
    const float* __restrict__ bm,
    const float* __restrict__ Psrc, const float* __restrict__ Pdst,
    float* __restrict__ agg, int E)
{
    __shared__ __align__(16) char smem[35328];
    unsigned short* ahi = (unsigned short*)smem;            // [64][136]
    unsigned short* alo = (unsigned short*)(smem + 17408);  // [64][136]
    int* sdh = (int*)(smem + 34816);                        // [64] (not overlaid)
    int* ssh = (int*)(smem + 35072);                        // [64] (not overlaid)
    float* ms = (float*)smem;                               // [64][132] overlay

    const int tid = threadIdx.x;
    const int w = tid >> 6;          // 0..7
    const int l = tid & 63;
    const int quad = l >> 4;
    const int l16 = l & 15;
    const int col = w * 16 + l16;    // this wave's column block

    // bijective XCD swizzle (m204 form)
    const int nb = gridDim.x;
    const int q = nb >> 3, rr = nb & 7;
    const int xcd = blockIdx.x & 7, bidx = blockIdx.x >> 3;
    const int bid = (xcd < rr ? xcd * (q + 1) : rr * (q + 1) + (xcd - rr) * q) + bidx;
    const int p0 = bid * 64;

    if (tid < 64) {
        const int p = p0 + tid;
        sdh[tid] = (p < E) ? sdst[p] : -1;
        ssh[tid] = (p < E) ? ssrc[p] : 0;
    }
    // no barrier: sdh/ssh first read after the he-phase barrier

    float4v acc[4];
#pragma unroll
    for (int mt = 0; mt < 4; ++mt) acc[mt] = (float4v)0.f;

    short8 mwh[4], mwl[4];   // mid-GEMM weight frags (filled during he epilogue)

    // ---- he phase: A-frags direct from pre-split efh/efl (quads 2,3 = K-pad) ----
    {
        const int g = col * 32 + quad * 8;
        const short8 bh = ld_s8(&wehT_h[g]);
        const short8 bl = ld_s8(&wehT_l[g]);
        const short8 zf = {0, 0, 0, 0, 0, 0, 0, 0};
        short8 ah[4], al[4];
#pragma unroll
        for (int mt = 0; mt < 4; ++mt) { ah[mt] = zf; al[mt] = zf; }
        if (quad < 2) {
#pragma unroll
            for (int mt = 0; mt < 4; ++mt) {
                const int row = mt * 16 + l16;
                if (p0 + row < E) {
                    ah[mt] = ld_s8(&efh[(size_t)(p0 + row) * 16 + quad * 8]);
                    al[mt] = ld_s8(&efl[(size_t)(p0 + row) * 16 + quad * 8]);
                }
            }
        }
        __builtin_amdgcn_s_setprio(1);
#pragma unroll
        for (int mt = 0; mt < 4; ++mt) {
            acc[mt] = __builtin_amdgcn_mfma_f32_16x16x32_bf16(ah[mt], bh, acc[mt], 0, 0, 0);
            acc[mt] = __builtin_amdgcn_mfma_f32_16x16x32_bf16(ah[mt], bl, acc[mt], 0, 0, 0);
            acc[mt] = __builtin_amdgcn_mfma_f32_16x16x32_bf16(al[mt], bh, acc[mt], 0, 0, 0);
        }
        __builtin_amdgcn_s_setprio(0);

        // pinned issue of mid-GEMM weights: latency hides under split+barrier
#pragma unroll
        for (int c = 0; c < 4; ++c) {
            const unsigned short* ph = &wmT_h[col * 128 + c * 32 + quad * 8];
            const unsigned short* pl = &wmT_l[col * 128 + c * 32 + quad * 8];
            asm volatile("global_load_dwordx4 %0, %1, off" : "=v"(mwh[c]) : "v"(ph) : "memory");
            asm volatile("global_load_dwordx4 %0, %1, off" : "=v"(mwl[c]) : "v"(pl) : "memory");
        }

        // bias + relu + split -> ahi/alo
        const float bcol = be[col];
#pragma unroll
        for (int mt = 0; mt < 4; ++mt) {
            float c[4];
#pragma unroll
            for (int r = 0; r < 4; ++r) c[r] = fmaxf(acc[mt][r] + bcol, 0.f);
            unsigned hp01, lp01, hp23, lp23;
            split_pk(c[0], c[1], hp01, lp01);
            split_pk(c[2], c[3], hp23, lp23);
            const int rb = (mt * 16 + quad * 4) * 136 + col;
            ahi[rb]       = (unsigned short)hp01;         alo[rb]       = (unsigned short)lp01;
            ahi[rb + 136] = (unsigned short)(hp01 >> 16); alo[rb + 136] = (unsigned short)(lp01 >> 16);
            ahi[rb + 272] = (unsigned short)hp23;         alo[rb + 272] = (unsigned short)lp23;
            ahi[rb + 408] = (unsigned short)(hp23 >> 16); alo[rb + 408] = (unsigned short)(lp23 >> 16);
        }
    }
    __syncthreads();
    // rule-18 fence: guarantee the asm weight loads have landed before use
    asm volatile("s_waitcnt vmcnt(0)" ::: "memory");
    __builtin_amdgcn_sched_barrier(0);

    // ---- mid GEMM: K=128, weights already in registers ----
#pragma unroll
    for (int mt = 0; mt < 4; ++mt) acc[mt] = (float4v)0.f;

#pragma unroll
    for (int c = 0; c < 4; ++c) {
        const int k0 = c * 32;
#pragma unroll
        for (int mt = 0; mt < 4; ++mt) {
            const int base = (mt * 16 + l16) * 136 + k0 + quad * 8;
            const short8 ah = ld_s8(&ahi[base]);
            const short8 al = ld_s8(&alo[base]);
            __builtin_amdgcn_s_setprio(1);
            acc[mt] = __builtin_amdgcn_mfma_f32_16x16x32_bf16(ah, mwh[c], acc[mt], 0, 0, 0);
            acc[mt] = __builtin_amdgcn_mfma_f32_16x16x32_bf16(ah, mwl[c], acc[mt], 0, 0, 0);
            acc[mt] = __builtin_amdgcn_mfma_f32_16x16x32_bf16(al, mwh[c], acc[mt], 0, 0, 0);
            __builtin_amdgcn_s_setprio(0);
        }
    }
    __syncthreads();   // ahi/alo reads done; safe to overlay ms

    // ---- hoisted reduce prologue: segment ids + pinned gathers ----
    const int j = tid & 127;
    const int rbase = (tid >> 7) * 16;   // 0,16,32,48 — wave-uniform
    int dseg[16], sseg[16];
#pragma unroll
    for (int k = 0; k < 16; ++k) {
        dseg[k] = __builtin_amdgcn_readfirstlane(sdh[rbase + k]);
        sseg[k] = __builtin_amdgcn_readfirstlane(ssh[rbase + k]);
    }
    float ps[16];
#pragma unroll
    for (int k = 0; k < 16; ++k) {
        const float* ap = &Psrc[(size_t)sseg[k] * 128 + j];
        asm volatile("global_load_dword %0, %1, off" : "=v"(ps[k]) : "v"(ap) : "memory");
    }
    float pd0;
    {
        const int d0i = (dseg[0] >= 0) ? dseg[0] : 0;
        const float* ap = &Pdst[(size_t)d0i * 128 + j];
        asm volatile("global_load_dword %0, %1, off" : "=v"(pd0) : "v"(ap) : "memory");
    }

    // ---- spill to ms (MFMA layout -> row layout); gathers fly underneath ----
#pragma unroll
    for (int mt = 0; mt < 4; ++mt)
#pragma unroll
        for (int r = 0; r < 4; ++r)
            ms[(mt * 16 + quad * 4 + r) * 132 + col] = acc[mt][r];
    // raw lgkm-only barrier: drains the ds_writes (LDS) without retiring the
    // in-flight vmem gathers.
    asm volatile("s_waitcnt lgkmcnt(0)" ::: "memory");
    __builtin_amdgcn_s_barrier();
    asm volatile("s_waitcnt vmcnt(0)" ::: "memory");
    __builtin_amdgcn_sched_barrier(0);

    // ---- fused epilogue + run-length reduction (scalarized control) ----
    {
        const float bmj = bm[j];
        float a = 0.f;
        float pdj = pd0;
        int dprev = dseg[0];
#pragma unroll
        for (int k = 0; k < 16; ++k) {
            const int d = dseg[k];
            const float v = ms[(rbase + k) * 132 + j];
            if (d >= 0) {
                if (d != dprev) { pdj = Pdst[(size_t)d * 128 + j]; dprev = d; }
                a += fmaxf(v + bmj + ps[k] + pdj, 0.f);
                const int dn = (k == 15) ? -1 : dseg[k + 1];
                if (dn != d) {
                    atomicAdd(&agg[(size_t)d * 128 + j], a);
                    a = 0.f;
                }
            }
        }
    }
}

// ---- readout: two demands per wave, vectorized dp/df loads, 4096 blocks ----
__global__ __launch_bounds__(256) void readout_kernel(
    const float* __restrict__ Qs, const float* __restrict__ Qd,
    const float* __restrict__ df, const int* __restrict__ dp,
    const float* __restrict__ Wd, const float* __restrict__ b1,
    const float* __restrict__ w2, const float* __restrict__ b2,
    float* __restrict__ out, int D)
{
    __shared__ float wd[8 * 128];
    const int tid = threadIdx.x;
    const int wv = tid >> 6;
    const int l = tid & 63;
    for (int idx = tid; idx < 8 * 128; idx += 256) wd[idx] = Wd[idx];
    __syncthreads();
    const float c1a = b1[l], c1b = b1[l + 64];
    const float w2a = w2[l], w2b = w2[l + 64];
    const float bb = b2[0];
    for (int d0 = blockIdx.x * 8 + wv * 2; d0 < D; d0 += gridDim.x * 8) {
        const int d1 = min(d0 + 1, D - 1);
        const int2 pA = *(const int2*)&dp[2 * d0];
        const int2 pB = *(const int2*)&dp[2 * d1];
        // vectorized df rows (32B-aligned): components consumed in k-order
        const float4 fA0 = *(const float4*)&df[(size_t)d0 * 8];
        const float4 fA1 = *(const float4*)&df[(size_t)d0 * 8 + 4];
        const float4 fB0 = *(const float4*)&df[(size_t)d1 * 8];
        const float4 fB1 = *(const float4*)&df[(size_t)d1 * 8 + 4];
        float a0 = c1a + Qs[(size_t)pA.x * 128 + l] + Qd[(size_t)pA.y * 128 + l];
        float b0 = c1b + Qs[(size_t)pA.x * 128 + l + 64] + Qd[(size_t)pA.y * 128 + l + 64];
        float a1 = c1a + Qs[(size_t)pB.x * 128 + l] + Qd[(size_t)pB.y * 128 + l];
        float b1x = c1b + Qs[(size_t)pB.x * 128 + l + 64] + Qd[(size_t)pB.y * 128 + l + 64];
        const float fa[8] = {fA0.x, fA0.y, fA0.z, fA0.w, fA1.x, fA1.y, fA1.z, fA1.w};
        const float fb[8] = {fB0.x, fB0.y, fB0.z, fB0.w, fB1.x, fB1.y, fB1.z, fB1.w};
#pragma unroll
        for (int k = 0; k < 8; ++k) {
            a0 = fmaf(fa[k], wd[k * 128 + l], a0);
            b0 = fmaf(fa[k], wd[k * 128 + l + 64], b0);
            a1 = fmaf(fb[k], wd[k * 128 + l], a1);
            b1x = fmaf(fb[k], wd[k * 128 + l + 64], b1x);
        }
        float v0 = fmaxf(a0, 0.f) * w2a + fmaxf(b0, 0.f) * w2b;
        float v1 = fmaxf(a1, 0.f) * w2a + fmaxf(b1x, 0.f) * w2b;
#pragma unroll
        for (int o = 32; o > 0; o >>= 1) {
            v0 += __shfl_down(v0, o);
            v1 += __shfl_down(v1, o);
        }
        if (l == 0) {
            out[d0] = 1.f / (1.f + __expf(-(v0 + bb)));
            if (d1 != d0) out[d1] = 1.f / (1.f + __expf(-(v1 + bb)));
        }
    }
}

extern "C" void kernel_launch(void* const* d_in, const int* in_sizes, int n_in,
                              void* d_out, int out_size, void* d_ws, size_t ws_size,
                              hipStream_t stream)
{
    const float* node_feats   = (const float*)d_in[0];
    const float* edge_feats   = (const float*)d_in[1];
    const float* demand_feats = (const float*)d_in[2];
    const int*   ei = (const int*)d_in[3];
    const int*   dp = (const int*)d_in[4];
    const float* W_node = (const float*)d_in[5];
    const float* b_node = (const float*)d_in[6];
    const float* W_edge = (const float*)d_in[7];
    const float* b_edge = (const float*)d_in[8];
    const float* Wm[2] = {(const float*)d_in[9],  (const float*)d_in[13]};
    const float* bm[2] = {(const float*)d_in[10], (const float*)d_in[14]};
    const float* Wu[2] = {(const float*)d_in[11], (const float*)d_in[15]};
    const float* bu[2] = {(const float*)d_in[12], (const float*)d_in[16]};
    const float* W_r1 = (const float*)d_in[17];
    const float* b_r1 = (const float*)d_in[18];
    const float* W_r2 = (const float*)d_in[19];
    const float* b_r2 = (const float*)d_in[20];
    float* out = (float*)d_out;

    const int NN = in_sizes[0] / 32;   // 20000
    const int NE = in_sizes[3] / 2;    // 640000
    const int ND = in_sizes[4] / 2;    // 100000

    float* B0 = (float*)d_ws;
    float* B1 = B0 + (size_t)NN * 128;
    float* B2 = B1 + (size_t)NN * 128;
    float* B3 = B2 + (size_t)NN * 128;
    int* cnt  = (int*)(B3 + (size_t)NN * 128);
    int* fill = cnt + NN;
    int* ssrc = fill + NN;
    int* sdst = ssrc + NE;
    // small-weight pair: [wehT | wnT] hi then lo (2 x 4096 each)
    unsigned short* wsm_h = (unsigned short*)(sdst + NE);
    unsigned short* wsm_l = wsm_h + 2 * 4096;
    unsigned short* wehT_h = wsm_h;          unsigned short* wehT_l = wsm_l;
    unsigned short* wnT_h  = wsm_h + 4096;   unsigned short* wnT_l  = wsm_l + 4096;
    unsigned short* spl8_h = wsm_l + 2 * 4096;          // 8 x 16384
    unsigned short* spl8_l = spl8_h + 8 * 16384;
    unsigned short* wu_h   = spl8_l + 8 * 16384;        // 2 x 32768
    unsigned short* wu_l   = wu_h + 2 * 32768;
    // pre-permuted, pre-split edge feats (dst-sorted): 2 x NE x 16 ushorts
    unsigned short* efh = wu_l + 2 * 32768;
    unsigned short* efl = efh + (size_t)NE * 16;

    unsigned short* wm0mid_h = spl8_h + 0 * 16384; unsigned short* wm0mid_l = spl8_l + 0 * 16384;
    unsigned short* wm1mid_h = spl8_h + 1 * 16384; unsigned short* wm1mid_l = spl8_l + 1 * 16384;
    unsigned short* wm0a_h   = spl8_h + 2 * 16384; unsigned short* wm0a_l   = spl8_l + 2 * 16384;
    unsigned short* wm0d_h   = spl8_h + 3 * 16384; unsigned short* wm0d_l   = spl8_l + 3 * 16384;
    unsigned short* wm1a_h   = spl8_h + 4 * 16384; unsigned short* wm1a_l   = spl8_l + 4 * 16384;
    unsigned short* wm1d_h   = spl8_h + 5 * 16384; unsigned short* wm1d_l   = spl8_l + 5 * 16384;
    unsigned short* wr1a_h   = spl8_h + 6 * 16384; unsigned short* wr1a_l   = spl8_l + 6 * 16384;
    unsigned short* wr1b_h   = spl8_h + 7 * 16384; unsigned short* wr1b_l   = spl8_l + 7 * 16384;
    unsigned short* wu0_h = wu_h + 0;      unsigned short* wu0_l = wu_l + 0;
    unsigned short* wu1_h = wu_h + 32768;  unsigned short* wu1_l = wu_l + 32768;

    const int nbN = (NN + 63) / 64;
    const int nbE = (NE + 63) / 64;

    // ---- weight prep ----
    tsplit_pair_kernel<<<32, 256, 0, stream>>>(W_edge, 16, W_node, 32, wsm_h, wsm_l);
    {
        SrcList8 s8;
        s8.p[0] = Wm[0] + 128 * 128; s8.p[1] = Wm[1] + 128 * 128;
        s8.p[2] = Wm[0];             s8.p[3] = Wm[0] + 256 * 128;
        s8.p[4] = Wm[1];             s8.p[5] = Wm[1] + 256 * 128;
        s8.p[6] = W_r1;              s8.p[7] = W_r1 + 128 * 128;
        tsplit8_kernel<<<512, 256, 0, stream>>>(s8, spl8_h, spl8_l);
    }
    {
        SrcList2 s2;
        s2.p[0] = Wu[0]; s2.p[1] = Wu[1];
        tsplit2_kernel<<<256, 256, 0, stream>>>(s2, wu_h, wu_l);
    }

    // ---- sort edges by dst (scatter also permutes+splits edge feats) ----
    hipMemsetAsync(cnt, 0, NN * sizeof(int), stream);
    hist_kernel<<<(NE + 255) / 256, 256, 0, stream>>>(ei, cnt, NE);
    scan_kernel<<<1, 256, 0, stream>>>(cnt, fill, NN);
    scatter_kernel<<<(NE + 255) / 256, 256, 0, stream>>>(ei, edge_feats, fill,
                                                         ssrc, sdst, efh, efl, NE);

    // ---- encode + layer-0 projections ----
    encode_mfma_kernel<<<nbN, 256, 0, stream>>>(node_feats, wnT_h, wnT_l, b_node,
                                                wm0a_h, wm0a_l, wm0d_h, wm0d_l,
                                                B0, B1, B2, NN);
    // ---- layer 0 edge ----
    hipMemsetAsync(B3, 0, (size_t)NN * 128 * sizeof(float), stream);
    edge_msg_mfma_kernel<<<nbE, 512, 0, stream>>>(efh, efl, ssrc, sdst,
                                                  wehT_h, wehT_l, b_edge,
                                                  wm0mid_h, wm0mid_l, bm[0], B1, B2, B3, NE);
    // ---- update 0 + layer-1 projections (zeros B3 after reading it) ----
    update_mfma_kernel<<<nbN, 256, 0, stream>>>(B0, B3, wu0_h, wu0_l, bu[0],
                                                wm1a_h, wm1a_l, wm1d_h, wm1d_l,
                                                B0, B1, B2, NN);
    // ---- layer 1 edge (B3 already zeroed by update 0) ----
    edge_msg_mfma_kernel<<<nbE, 512, 0, stream>>>(efh, efl, ssrc, sdst,
                                                  wehT_h, wehT_l, b_edge,
                                                  wm1mid_h, wm1mid_l, bm[1], B1, B2, B3, NE);
    // ---- update 1 + readout projections ----
    update_mfma_kernel<<<nbN, 256, 0, stream>>>(B0, B3, wu1_h, wu1_l, bu[1],
                                                wr1a_h, wr1a_l, wr1b_h, wr1b_l,
                                                B0, B1, B2, NN);
    // ---- readout ----
    readout_kernel<<<4096, 256, 0, stream>>>(B1, B2, demand_feats, dp,
                                             W_r1 + 256 * 128, b_r1, W_r2, b_r2, out, ND);
}

// Round 18
// 556.998 us; speedup vs baseline: 1.0189x; 1.0189x over previous
//
#include <hip/hip_runtime.h>
#include <hip/hip_bf16.h>

using short8  = __attribute__((ext_vector_type(8))) short;
using float4v = __attribute__((ext_vector_type(4))) float;

__device__ __forceinline__ float4 f4zero() { return make_float4(0.f, 0.f, 0.f, 0.f); }

__device__ __forceinline__ float bfhi2f(unsigned short u) {
    return __uint_as_float(((unsigned int)u) << 16);
}
__device__ __forceinline__ unsigned short f2bf_rn(float x) {
    unsigned int u = __float_as_uint(x);
    u += 0x7FFFu + ((u >> 16) & 1u);
    return (unsigned short)(u >> 16);
}
__device__ __forceinline__ void split_bf(float v, unsigned short& h, unsigned short& l) {
    h = f2bf_rn(v);
    l = f2bf_rn(v - bfhi2f(h));
}
// packed pair convert: dst.lo16 = bf16(a), dst.hi16 = bf16(b) — single VALU op
__device__ __forceinline__ unsigned cvt_pk_bf16(float a, float b) {
    unsigned r;
    asm("v_cvt_pk_bf16_f32 %0, %1, %2" : "=v"(r) : "v"(a), "v"(b));
    return r;
}
// hi/lo split of a pair. Self-correcting: lo = x - hi exactly compensates hi rounding.
__device__ __forceinline__ void split_pk(float x, float y, unsigned& hp, unsigned& lp) {
    hp = cvt_pk_bf16(x, y);
    const float hx = __uint_as_float(hp << 16);
    const float hy = __uint_as_float(hp & 0xFFFF0000u);
    lp = cvt_pk_bf16(x - hx, y - hy);
}
__device__ __forceinline__ short8 ld_s8(const unsigned short* p) {   // 16B-aligned
    return *(const short8*)p;
}
union U8 { short8 s; uint4 u; };

// ---------------- weight prep ----------------
__global__ __launch_bounds__(256) void tsplit_pair_kernel(
    const float* __restrict__ W0, int K0, const float* __restrict__ W1, int K1,
    unsigned short* __restrict__ oh, unsigned short* __restrict__ ol)
{
    const int m = blockIdx.x >> 4;
    const int idx = (blockIdx.x & 15) * 256 + threadIdx.x;   // 0..4095
    const int n = idx >> 5, k = idx & 31;
    const float* W = m ? W1 : W0;
    const int K = m ? K1 : K0;
    const float v = (k < K) ? W[(size_t)k * 128 + n] : 0.f;
    unsigned short h, l;
    split_bf(v, h, l);
    oh[m * 4096 + idx] = h; ol[m * 4096 + idx] = l;
}

struct SrcList8 { const float* p[8]; };
__global__ __launch_bounds__(256) void tsplit8_kernel(
    SrcList8 src, unsigned short* __restrict__ dh, unsigned short* __restrict__ dl)
{
    const int m = blockIdx.x >> 6;
    const int idx = (blockIdx.x & 63) * 256 + threadIdx.x;  // 0..16383
    const int n = idx >> 7, k = idx & 127;
    const float v = src.p[m][(size_t)k * 128 + n];
    unsigned short h, l;
    split_bf(v, h, l);
    dh[m * 16384 + idx] = h; dl[m * 16384 + idx] = l;
}

struct SrcList2 { const float* p[2]; };
__global__ __launch_bounds__(256) void tsplit2_kernel(
    SrcList2 src, unsigned short* __restrict__ dh, unsigned short* __restrict__ dl)
{
    const int m = blockIdx.x >> 7;
    const int idx = (blockIdx.x & 127) * 256 + threadIdx.x; // 0..32767
    const int n = idx >> 8, k = idx & 255;
    const float v = src.p[m][(size_t)k * 128 + n];
    unsigned short h, l;
    split_bf(v, h, l);
    dh[m * 32768 + idx] = h; dl[m * 32768 + idx] = l;
}

// ---------------- sort pipeline ----------------
__global__ __launch_bounds__(256) void hist_kernel(
    const int* __restrict__ ei, int* __restrict__ cnt, int E)
{
    const int i = blockIdx.x * blockDim.x + threadIdx.x;
    if (i < E) atomicAdd(&cnt[ei[E + i]], 1);
}

__global__ __launch_bounds__(256) void scan_kernel(
    const int* __restrict__ cnt, int* __restrict__ fill, int n)
{
    __shared__ int part[256];
    const int tid = threadIdx.x;
    const int chunk = (n + 255) / 256;
    const int beg = tid * chunk;
    const int end = min(beg + chunk, n);
    int s = 0;
    for (int i = beg; i < end; ++i) s += cnt[i];
    part[tid] = s;
    __syncthreads();
    for (int off = 1; off < 256; off <<= 1) {
        const int v = (tid >= off) ? part[tid - off] : 0;
        __syncthreads();
        part[tid] += v;
        __syncthreads();
    }
    int prefix = (tid == 0) ? 0 : part[tid - 1];
    for (int i = beg; i < end; ++i) { fill[i] = prefix; prefix += cnt[i]; }
}

// scatter fused with edge-feat permute+split (R10 proven)
__global__ __launch_bounds__(256) void scatter_kernel(
    const int* __restrict__ ei, const float* __restrict__ ef,
    int* __restrict__ fill, int* __restrict__ ssrc, int* __restrict__ sdst,
    unsigned short* __restrict__ efh, unsigned short* __restrict__ efl, int E)
{
    const int e = blockIdx.x * blockDim.x + threadIdx.x;
    if (e < E) {
        const int d = ei[E + e];
        const int pos = atomicAdd(&fill[d], 1);
        ssrc[pos] = ei[e];
        sdst[pos] = d;
        const float4 v0 = *(const float4*)&ef[(size_t)e * 16];
        const float4 v1 = *(const float4*)&ef[(size_t)e * 16 + 4];
        const float4 v2 = *(const float4*)&ef[(size_t)e * 16 + 8];
        const float4 v3 = *(const float4*)&ef[(size_t)e * 16 + 12];
        U8 H0, L0, H1, L1;
        unsigned h, lo2;
        split_pk(v0.x, v0.y, h, lo2); H0.u.x = h; L0.u.x = lo2;
        split_pk(v0.z, v0.w, h, lo2); H0.u.y = h; L0.u.y = lo2;
        split_pk(v1.x, v1.y, h, lo2); H0.u.z = h; L0.u.z = lo2;
        split_pk(v1.z, v1.w, h, lo2); H0.u.w = h; L0.u.w = lo2;
        split_pk(v2.x, v2.y, h, lo2); H1.u.x = h; L1.u.x = lo2;
        split_pk(v2.z, v2.w, h, lo2); H1.u.y = h; L1.u.y = lo2;
        split_pk(v3.x, v3.y, h, lo2); H1.u.z = h; L1.u.z = lo2;
        split_pk(v3.z, v3.w, h, lo2); H1.u.w = h; L1.u.w = lo2;
        *(uint4*)&efh[(size_t)pos * 16]     = H0.u;
        *(uint4*)&efh[(size_t)pos * 16 + 8] = H1.u;
        *(uint4*)&efl[(size_t)pos * 16]     = L0.u;
        *(uint4*)&efl[(size_t)pos * 16 + 8] = L1.u;
    }
}

// =====================================================================
// Fused node kernels — 64-row tiles, 256 threads (R14 fused projection)
// =====================================================================
__device__ __forceinline__ void node_epilogue_proj(
    float4v (&acc)[4][2], unsigned short* ahi, unsigned short* alo,
    const float* bias, const unsigned short* v1h, const unsigned short* v1l,
    const unsigned short* v2h, const unsigned short* v2l,
    float* C, float* P1, float* P2,
    int r0, int M, int w, int quad, int l16)
{
    __syncthreads();
#pragma unroll
    for (int t = 0; t < 2; ++t) {
        const int col = (2 * w + t) * 16 + l16;
        const float bcol = bias[col];
#pragma unroll
        for (int mt = 0; mt < 4; ++mt) {
            float c[4];
#pragma unroll
            for (int r = 0; r < 4; ++r) {
                const int row = mt * 16 + quad * 4 + r;
                c[r] = fmaxf(acc[mt][t][r] + bcol, 0.f);
                if (r0 + row < M) C[(size_t)(r0 + row) * 128 + col] = c[r];
            }
            unsigned hp01, lp01, hp23, lp23;
            split_pk(c[0], c[1], hp01, lp01);
            split_pk(c[2], c[3], hp23, lp23);
            const int rb = (mt * 16 + quad * 4) * 136 + col;
            ahi[rb]       = (unsigned short)hp01;         alo[rb]       = (unsigned short)lp01;
            ahi[rb + 136] = (unsigned short)(hp01 >> 16); alo[rb + 136] = (unsigned short)(lp01 >> 16);
            ahi[rb + 272] = (unsigned short)hp23;         alo[rb + 272] = (unsigned short)lp23;
            ahi[rb + 408] = (unsigned short)(hp23 >> 16); alo[rb + 408] = (unsigned short)(lp23 >> 16);
        }
    }
    __syncthreads();

    // fused dual projection: one pass over c4/mt, A-frags read once
    float4v pa[4][2], pb[4][2];
#pragma unroll
    for (int mt = 0; mt < 4; ++mt)
#pragma unroll
        for (int t = 0; t < 2; ++t) { pa[mt][t] = (float4v)0.f; pb[mt][t] = (float4v)0.f; }
#pragma unroll
    for (int c4 = 0; c4 < 4; ++c4) {
        const int k0 = c4 * 32;
        short8 b1h[2], b1l[2], b2h[2], b2l[2];
#pragma unroll
        for (int t = 0; t < 2; ++t) {
            const int g = ((2 * w + t) * 16 + l16) * 128 + k0 + quad * 8;
            b1h[t] = ld_s8(&v1h[g]);
            b1l[t] = ld_s8(&v1l[g]);
            b2h[t] = ld_s8(&v2h[g]);
            b2l[t] = ld_s8(&v2l[g]);
        }
#pragma unroll
        for (int mt = 0; mt < 4; ++mt) {
            const int base = (mt * 16 + l16) * 136 + k0 + quad * 8;
            const short8 ah = ld_s8(&ahi[base]);
            const short8 al = ld_s8(&alo[base]);
#pragma unroll
            for (int t = 0; t < 2; ++t) {
                pa[mt][t] = __builtin_amdgcn_mfma_f32_16x16x32_bf16(ah, b1h[t], pa[mt][t], 0, 0, 0);
                pa[mt][t] = __builtin_amdgcn_mfma_f32_16x16x32_bf16(ah, b1l[t], pa[mt][t], 0, 0, 0);
                pa[mt][t] = __builtin_amdgcn_mfma_f32_16x16x32_bf16(al, b1h[t], pa[mt][t], 0, 0, 0);
                pb[mt][t] = __builtin_amdgcn_mfma_f32_16x16x32_bf16(ah, b2h[t], pb[mt][t], 0, 0, 0);
                pb[mt][t] = __builtin_amdgcn_mfma_f32_16x16x32_bf16(ah, b2l[t], pb[mt][t], 0, 0, 0);
                pb[mt][t] = __builtin_amdgcn_mfma_f32_16x16x32_bf16(al, b2h[t], pb[mt][t], 0, 0, 0);
            }
        }
    }
#pragma unroll
    for (int t = 0; t < 2; ++t) {
        const int col = (2 * w + t) * 16 + l16;
#pragma unroll
        for (int mt = 0; mt < 4; ++mt)
#pragma unroll
            for (int r = 0; r < 4; ++r) {
                const int row = mt * 16 + quad * 4 + r;
                if (r0 + row < M) {
                    P1[(size_t)(r0 + row) * 128 + col] = pa[mt][t][r];
                    P2[(size_t)(r0 + row) * 128 + col] = pb[mt][t][r];
                }
            }
    }
}

__global__ __launch_bounds__(256) void encode_mfma_kernel(
    const float* __restrict__ X,
    const unsigned short* __restrict__ wTh, const unsigned short* __restrict__ wTl,
    const float* __restrict__ bias,
    const unsigned short* __restrict__ v1h, const unsigned short* __restrict__ v1l,
    const unsigned short* __restrict__ v2h, const unsigned short* __restrict__ v2l,
    float* __restrict__ C, float* __restrict__ P1, float* __restrict__ P2, int M)
{
    __shared__ __align__(16) char smem[34816];
    unsigned short* ahi = (unsigned short*)smem;
    unsigned short* alo = (unsigned short*)(smem + 17408);
    const int tid = threadIdx.x;
    const int w = tid >> 6, l = tid & 63, quad = l >> 4, l16 = l & 15;
    const int r0 = blockIdx.x * 64;

#pragma unroll
    for (int rep = 0; rep < 2; ++rep) {
        const int fid = tid + rep * 256;
        const int row = fid >> 3, kq = fid & 7;
        float4 v = f4zero();
        if (r0 + row < M) v = *(const float4*)&X[(size_t)(r0 + row) * 32 + 4 * kq];
        unsigned hpx, lpx, hpy, lpy;
        split_pk(v.x, v.y, hpx, lpx);
        split_pk(v.z, v.w, hpy, lpy);
        uint2 hp; hp.x = hpx; hp.y = hpy;
        uint2 lp; lp.x = lpx; lp.y = lpy;
        *(uint2*)&ahi[row * 136 + 4 * kq] = hp;
        *(uint2*)&alo[row * 136 + 4 * kq] = lp;
    }
    __syncthreads();

    float4v acc[4][2];
#pragma unroll
    for (int mt = 0; mt < 4; ++mt)
#pragma unroll
        for (int t = 0; t < 2; ++t) acc[mt][t] = (float4v)0.f;

    {
        short8 bh[2], bl[2];
#pragma unroll
        for (int t = 0; t < 2; ++t) {
            const int g = ((2 * w + t) * 16 + l16) * 32 + quad * 8;
            bh[t] = ld_s8(&wTh[g]);
            bl[t] = ld_s8(&wTl[g]);
        }
#pragma unroll
        for (int mt = 0; mt < 4; ++mt) {
            const int base = (mt * 16 + l16) * 136 + quad * 8;
            const short8 ah = ld_s8(&ahi[base]);
            const short8 al = ld_s8(&alo[base]);
#pragma unroll
            for (int t = 0; t < 2; ++t) {
                acc[mt][t] = __builtin_amdgcn_mfma_f32_16x16x32_bf16(ah, bh[t], acc[mt][t], 0, 0, 0);
                acc[mt][t] = __builtin_amdgcn_mfma_f32_16x16x32_bf16(ah, bl[t], acc[mt][t], 0, 0, 0);
                acc[mt][t] = __builtin_amdgcn_mfma_f32_16x16x32_bf16(al, bh[t], acc[mt][t], 0, 0, 0);
            }
        }
    }
    node_epilogue_proj(acc, ahi, alo, bias, v1h, v1l, v2h, v2l, C, P1, P2, r0, M, w, quad, l16);
}

__global__ __launch_bounds__(256) void update_mfma_kernel(
    const float* __restrict__ A1, float* __restrict__ A2,
    const unsigned short* __restrict__ wTh, const unsigned short* __restrict__ wTl,
    const float* __restrict__ bias,
    const unsigned short* __restrict__ v1h, const unsigned short* __restrict__ v1l,
    const unsigned short* __restrict__ v2h, const unsigned short* __restrict__ v2l,
    float* __restrict__ C, float* __restrict__ P1, float* __restrict__ P2, int M)
{
    __shared__ __align__(16) char smem[34816];
    unsigned short* ahi = (unsigned short*)smem;
    unsigned short* alo = (unsigned short*)(smem + 17408);
    const int tid = threadIdx.x;
    const int w = tid >> 6, l = tid & 63, quad = l >> 4, l16 = l & 15;
    const int r0 = blockIdx.x * 64;

    float4v acc[4][2];
#pragma unroll
    for (int mt = 0; mt < 4; ++mt)
#pragma unroll
        for (int t = 0; t < 2; ++t) acc[mt][t] = (float4v)0.f;

    for (int half = 0; half < 2; ++half) {
        const float* A = half ? A2 : A1;
        if (half) __syncthreads();
#pragma unroll
        for (int rep = 0; rep < 8; ++rep) {
            const int fid = tid + rep * 256;
            const int row = fid >> 5, kq = fid & 31;
            float4 v = f4zero();
            if (r0 + row < M) v = *(const float4*)&A[(size_t)(r0 + row) * 128 + 4 * kq];
            unsigned hpx, lpx, hpy, lpy;
            split_pk(v.x, v.y, hpx, lpx);
            split_pk(v.z, v.w, hpy, lpy);
            uint2 hp; hp.x = hpx; hp.y = hpy;
            uint2 lp; lp.x = lpx; lp.y = lpy;
            *(uint2*)&ahi[row * 136 + 4 * kq] = hp;
            *(uint2*)&alo[row * 136 + 4 * kq] = lp;
            // zero the agg buffer as a side effect (after v is consumed)
            if (half == 1 && r0 + row < M)
                *(float4*)&A2[(size_t)(r0 + row) * 128 + 4 * kq] = f4zero();
        }
        __syncthreads();
#pragma unroll
        for (int c4 = 0; c4 < 4; ++c4) {
            const int k0 = c4 * 32;
            short8 bh[2], bl[2];
#pragma unroll
            for (int t = 0; t < 2; ++t) {
                const int g = ((2 * w + t) * 16 + l16) * 256 + half * 128 + k0 + quad * 8;
                bh[t] = ld_s8(&wTh[g]);
                bl[t] = ld_s8(&wTl[g]);
            }
#pragma unroll
            for (int mt = 0; mt < 4; ++mt) {
                const int base = (mt * 16 + l16) * 136 + k0 + quad * 8;
                const short8 ah = ld_s8(&ahi[base]);
                const short8 al = ld_s8(&alo[base]);
#pragma unroll
                for (int t = 0; t < 2; ++t) {
                    acc[mt][t] = __builtin_amdgcn_mfma_f32_16x16x32_bf16(ah, bh[t], acc[mt][t], 0, 0, 0);
                    acc[mt][t] = __builtin_amdgcn_mfma_f32_16x16x32_bf16(ah, bl[t], acc[mt][t], 0, 0, 0);
                    acc[mt][t] = __builtin_amdgcn_mfma_f32_16x16x32_bf16(al, bh[t], acc[mt][t], 0, 0, 0);
                }
            }
        }
    }
    node_epilogue_proj(acc, ahi, alo, bias, v1h, v1l, v2h, v2l, C, P1, P2, r0, M, w, quad, l16);
}

// ---- fused edge path: 64-edge tiles, 512 threads (8 waves x 16 cols) ----
// R16 form (measured best ~136.0 µs): pinned mid-weight hoist + hoisted
// reduce gathers + lgkm-only spill barrier + scalarized reduce.
__global__ __launch_bounds__(512, 8) void edge_msg_mfma_kernel(
    const unsigned short* __restrict__ efh, const unsigned short* __restrict__ efl,
    const int* __restrict__ ssrc, const int* __restrict__ sdst,
    const unsigned short* __restrict__ wehT_h, const unsigned short* __restrict__ wehT_l,
    const float* __restrict__ be,
    const unsigned short* __restrict__ wmT_h, const unsigned short* __restrict__ wmT_l,
    const float* __restrict__ bm,
    const float* __restrict__ Psrc, const float* __restrict__ Pdst,
    float* __restrict__ agg, int E)
{
    __shared__ __align__(16) char smem[35328];
    unsigned short* ahi = (unsigned short*)smem;            // [64][136]
    unsigned short* alo = (unsigned short*)(smem + 17408);  // [64][136]
    int* sdh = (int*)(smem + 34816);                        // [64] (not overlaid)
    int* ssh = (int*)(smem + 35072);                        // [64] (not overlaid)
    float* ms = (float*)smem;                               // [64][132] overlay

    const int tid = threadIdx.x;
    const int w = tid >> 6;          // 0..7
    const int l = tid & 63;
    const int quad = l >> 4;
    const int l16 = l & 15;
    const int col = w * 16 + l16;    // this wave's column block

    // bijective XCD swizzle (m204 form)
    const int nb = gridDim.x;
    const int q = nb >> 3, rr = nb & 7;
    const int xcd = blockIdx.x & 7, bidx = blockIdx.x >> 3;
    const int bid = (xcd < rr ? xcd * (q + 1) : rr * (q + 1) + (xcd - rr) * q) + bidx;
    const int p0 = bid * 64;

    if (tid < 64) {
        const int p = p0 + tid;
        sdh[tid] = (p < E) ? sdst[p] : -1;
        ssh[tid] = (p < E) ? ssrc[p] : 0;
    }
    // no barrier: sdh/ssh first read after the he-phase barrier

    float4v acc[4];
#pragma unroll
    for (int mt = 0; mt < 4; ++mt) acc[mt] = (float4v)0.f;

    short8 mwh[4], mwl[4];   // mid-GEMM weight frags (filled during he epilogue)

    // ---- he phase: A-frags direct from pre-split efh/efl (quads 2,3 = K-pad) ----
    {
        const int g = col * 32 + quad * 8;
        const short8 bh = ld_s8(&wehT_h[g]);
        const short8 bl = ld_s8(&wehT_l[g]);
        const short8 zf = {0, 0, 0, 0, 0, 0, 0, 0};
        short8 ah[4], al[4];
#pragma unroll
        for (int mt = 0; mt < 4; ++mt) { ah[mt] = zf; al[mt] = zf; }
        if (quad < 2) {
#pragma unroll
            for (int mt = 0; mt < 4; ++mt) {
                const int row = mt * 16 + l16;
                if (p0 + row < E) {
                    ah[mt] = ld_s8(&efh[(size_t)(p0 + row) * 16 + quad * 8]);
                    al[mt] = ld_s8(&efl[(size_t)(p0 + row) * 16 + quad * 8]);
                }
            }
        }
        __builtin_amdgcn_s_setprio(1);
#pragma unroll
        for (int mt = 0; mt < 4; ++mt) {
            acc[mt] = __builtin_amdgcn_mfma_f32_16x16x32_bf16(ah[mt], bh, acc[mt], 0, 0, 0);
            acc[mt] = __builtin_amdgcn_mfma_f32_16x16x32_bf16(ah[mt], bl, acc[mt], 0, 0, 0);
            acc[mt] = __builtin_amdgcn_mfma_f32_16x16x32_bf16(al[mt], bh, acc[mt], 0, 0, 0);
        }
        __builtin_amdgcn_s_setprio(0);

        // pinned issue of mid-GEMM weights: latency hides under split+barrier
#pragma unroll
        for (int c = 0; c < 4; ++c) {
            const unsigned short* ph = &wmT_h[col * 128 + c * 32 + quad * 8];
            const unsigned short* pl = &wmT_l[col * 128 + c * 32 + quad * 8];
            asm volatile("global_load_dwordx4 %0, %1, off" : "=v"(mwh[c]) : "v"(ph) : "memory");
            asm volatile("global_load_dwordx4 %0, %1, off" : "=v"(mwl[c]) : "v"(pl) : "memory");
        }

        // bias + relu + split -> ahi/alo
        const float bcol = be[col];
#pragma unroll
        for (int mt = 0; mt < 4; ++mt) {
            float c[4];
#pragma unroll
            for (int r = 0; r < 4; ++r) c[r] = fmaxf(acc[mt][r] + bcol, 0.f);
            unsigned hp01, lp01, hp23, lp23;
            split_pk(c[0], c[1], hp01, lp01);
            split_pk(c[2], c[3], hp23, lp23);
            const int rb = (mt * 16 + quad * 4) * 136 + col;
            ahi[rb]       = (unsigned short)hp01;         alo[rb]       = (unsigned short)lp01;
            ahi[rb + 136] = (unsigned short)(hp01 >> 16); alo[rb + 136] = (unsigned short)(lp01 >> 16);
            ahi[rb + 272] = (unsigned short)hp23;         alo[rb + 272] = (unsigned short)lp23;
            ahi[rb + 408] = (unsigned short)(hp23 >> 16); alo[rb + 408] = (unsigned short)(lp23 >> 16);
        }
    }
    __syncthreads();
    // rule-18 fence: guarantee the asm weight loads have landed before use
    asm volatile("s_waitcnt vmcnt(0)" ::: "memory");
    __builtin_amdgcn_sched_barrier(0);

    // ---- mid GEMM: K=128, weights already in registers ----
#pragma unroll
    for (int mt = 0; mt < 4; ++mt) acc[mt] = (float4v)0.f;

#pragma unroll
    for (int c = 0; c < 4; ++c) {
        const int k0 = c * 32;
#pragma unroll
        for (int mt = 0; mt < 4; ++mt) {
            const int base = (mt * 16 + l16) * 136 + k0 + quad * 8;
            const short8 ah = ld_s8(&ahi[base]);
            const short8 al = ld_s8(&alo[base]);
            __builtin_amdgcn_s_setprio(1);
            acc[mt] = __builtin_amdgcn_mfma_f32_16x16x32_bf16(ah, mwh[c], acc[mt], 0, 0, 0);
            acc[mt] = __builtin_amdgcn_mfma_f32_16x16x32_bf16(ah, mwl[c], acc[mt], 0, 0, 0);
            acc[mt] = __builtin_amdgcn_mfma_f32_16x16x32_bf16(al, mwh[c], acc[mt], 0, 0, 0);
            __builtin_amdgcn_s_setprio(0);
        }
    }
    __syncthreads();   // ahi/alo reads done; safe to overlay ms

    // ---- hoisted reduce prologue: segment ids + pinned gathers ----
    const int j = tid & 127;
    const int rbase = (tid >> 7) * 16;   // 0,16,32,48 — wave-uniform
    int dseg[16], sseg[16];
#pragma unroll
    for (int k = 0; k < 16; ++k) {
        dseg[k] = __builtin_amdgcn_readfirstlane(sdh[rbase + k]);
        sseg[k] = __builtin_amdgcn_readfirstlane(ssh[rbase + k]);
    }
    float ps[16];
#pragma unroll
    for (int k = 0; k < 16; ++k) {
        const float* ap = &Psrc[(size_t)sseg[k] * 128 + j];
        asm volatile("global_load_dword %0, %1, off" : "=v"(ps[k]) : "v"(ap) : "memory");
    }
    float pd0;
    {
        const int d0i = (dseg[0] >= 0) ? dseg[0] : 0;
        const float* ap = &Pdst[(size_t)d0i * 128 + j];
        asm volatile("global_load_dword %0, %1, off" : "=v"(pd0) : "v"(ap) : "memory");
    }

    // ---- spill to ms (MFMA layout -> row layout); gathers fly underneath ----
#pragma unroll
    for (int mt = 0; mt < 4; ++mt)
#pragma unroll
        for (int r = 0; r < 4; ++r)
            ms[(mt * 16 + quad * 4 + r) * 132 + col] = acc[mt][r];
    // raw lgkm-only barrier: drains the ds_writes (LDS) without retiring the
    // in-flight vmem gathers.
    asm volatile("s_waitcnt lgkmcnt(0)" ::: "memory");
    __builtin_amdgcn_s_barrier();
    asm volatile("s_waitcnt vmcnt(0)" ::: "memory");
    __builtin_amdgcn_sched_barrier(0);

    // ---- fused epilogue + run-length reduction (scalarized control) ----
    {
        const float bmj = bm[j];
        float a = 0.f;
        float pdj = pd0;
        int dprev = dseg[0];
#pragma unroll
        for (int k = 0; k < 16; ++k) {
            const int d = dseg[k];
            const float v = ms[(rbase + k) * 132 + j];
            if (d >= 0) {
                if (d != dprev) { pdj = Pdst[(size_t)d * 128 + j]; dprev = d; }
                a += fmaxf(v + bmj + ps[k] + pdj, 0.f);
                const int dn = (k == 15) ? -1 : dseg[k + 1];
                if (dn != d) {
                    atomicAdd(&agg[(size_t)d * 128 + j], a);
                    a = 0.f;
                }
            }
        }
    }
}

// ---- readout: two demands per wave (R10 proven form) ----
__global__ __launch_bounds__(256) void readout_kernel(
    const float* __restrict__ Qs, const float* __restrict__ Qd,
    const float* __restrict__ df, const int* __restrict__ dp,
    const float* __restrict__ Wd, const float* __restrict__ b1,
    const float* __restrict__ w2, const float* __restrict__ b2,
    float* __restrict__ out, int D)
{
    __shared__ float wd[8 * 128];
    const int tid = threadIdx.x;
    const int wv = tid >> 6;
    const int l = tid & 63;
    for (int idx = tid; idx < 8 * 128; idx += 256) wd[idx] = Wd[idx];
    __syncthreads();
    const float c1a = b1[l], c1b = b1[l + 64];
    const float w2a = w2[l], w2b = w2[l + 64];
    const float bb = b2[0];
    for (int d0 = blockIdx.x * 8 + wv * 2; d0 < D; d0 += gridDim.x * 8) {
        const int d1 = min(d0 + 1, D - 1);
        const int sA = dp[2 * d0], tA = dp[2 * d0 + 1];
        const int sB = dp[2 * d1], tB = dp[2 * d1 + 1];
        float a0 = c1a + Qs[(size_t)sA * 128 + l] + Qd[(size_t)tA * 128 + l];
        float b0 = c1b + Qs[(size_t)sA * 128 + l + 64] + Qd[(size_t)tA * 128 + l + 64];
        float a1 = c1a + Qs[(size_t)sB * 128 + l] + Qd[(size_t)tB * 128 + l];
        float b1x = c1b + Qs[(size_t)sB * 128 + l + 64] + Qd[(size_t)tB * 128 + l + 64];
#pragma unroll
        for (int k = 0; k < 8; ++k) {
            const float f0 = df[(size_t)d0 * 8 + k];
            const float f1 = df[(size_t)d1 * 8 + k];
            a0 = fmaf(f0, wd[k * 128 + l], a0);
            b0 = fmaf(f0, wd[k * 128 + l + 64], b0);
            a1 = fmaf(f1, wd[k * 128 + l], a1);
            b1x = fmaf(f1, wd[k * 128 + l + 64], b1x);
        }
        float v0 = fmaxf(a0, 0.f) * w2a + fmaxf(b0, 0.f) * w2b;
        float v1 = fmaxf(a1, 0.f) * w2a + fmaxf(b1x, 0.f) * w2b;
#pragma unroll
        for (int o = 32; o > 0; o >>= 1) {
            v0 += __shfl_down(v0, o);
            v1 += __shfl_down(v1, o);
        }
        if (l == 0) {
            out[d0] = 1.f / (1.f + __expf(-(v0 + bb)));
            if (d1 != d0) out[d1] = 1.f / (1.f + __expf(-(v1 + bb)));
        }
    }
}

extern "C" void kernel_launch(void* const* d_in, const int* in_sizes, int n_in,
                              void* d_out, int out_size, void* d_ws, size_t ws_size,
                              hipStream_t stream)
{
    const float* node_feats   = (const float*)d_in[0];
    const float* edge_feats   = (const float*)d_in[1];
    const float* demand_feats = (const float*)d_in[2];
    const int*   ei = (const int*)d_in[3];
    const int*   dp = (const int*)d_in[4];
    const float* W_node = (const float*)d_in[5];
    const float* b_node = (const float*)d_in[6];
    const float* W_edge = (const float*)d_in[7];
    const float* b_edge = (const float*)d_in[8];
    const float* Wm[2] = {(const float*)d_in[9],  (const float*)d_in[13]};
    const float* bm[2] = {(const float*)d_in[10], (const float*)d_in[14]};
    const float* Wu[2] = {(const float*)d_in[11], (const float*)d_in[15]};
    const float* bu[2] = {(const float*)d_in[12], (const float*)d_in[16]};
    const float* W_r1 = (const float*)d_in[17];
    const float* b_r1 = (const float*)d_in[18];
    const float* W_r2 = (const float*)d_in[19];
    const float* b_r2 = (const float*)d_in[20];
    float* out = (float*)d_out;

    const int NN = in_sizes[0] / 32;   // 20000
    const int NE = in_sizes[3] / 2;    // 640000
    const int ND = in_sizes[4] / 2;    // 100000

    float* B0 = (float*)d_ws;
    float* B1 = B0 + (size_t)NN * 128;
    float* B2 = B1 + (size_t)NN * 128;
    float* B3 = B2 + (size_t)NN * 128;
    int* cnt  = (int*)(B3 + (size_t)NN * 128);
    int* fill = cnt + NN;
    int* ssrc = fill + NN;
    int* sdst = ssrc + NE;
    // small-weight pair: [wehT | wnT] hi then lo (2 x 4096 each)
    unsigned short* wsm_h = (unsigned short*)(sdst + NE);
    unsigned short* wsm_l = wsm_h + 2 * 4096;
    unsigned short* wehT_h = wsm_h;          unsigned short* wehT_l = wsm_l;
    unsigned short* wnT_h  = wsm_h + 4096;   unsigned short* wnT_l  = wsm_l + 4096;
    unsigned short* spl8_h = wsm_l + 2 * 4096;          // 8 x 16384
    unsigned short* spl8_l = spl8_h + 8 * 16384;
    unsigned short* wu_h   = spl8_l + 8 * 16384;        // 2 x 32768
    unsigned short* wu_l   = wu_h + 2 * 32768;
    // pre-permuted, pre-split edge feats (dst-sorted): 2 x NE x 16 ushorts
    unsigned short* efh = wu_l + 2 * 32768;
    unsigned short* efl = efh + (size_t)NE * 16;

    unsigned short* wm0mid_h = spl8_h + 0 * 16384; unsigned short* wm0mid_l = spl8_l + 0 * 16384;
    unsigned short* wm1mid_h = spl8_h + 1 * 16384; unsigned short* wm1mid_l = spl8_l + 1 * 16384;
    unsigned short* wm0a_h   = spl8_h + 2 * 16384; unsigned short* wm0a_l   = spl8_l + 2 * 16384;
    unsigned short* wm0d_h   = spl8_h + 3 * 16384; unsigned short* wm0d_l   = spl8_l + 3 * 16384;
    unsigned short* wm1a_h   = spl8_h + 4 * 16384; unsigned short* wm1a_l   = spl8_l + 4 * 16384;
    unsigned short* wm1d_h   = spl8_h + 5 * 16384; unsigned short* wm1d_l   = spl8_l + 5 * 16384;
    unsigned short* wr1a_h   = spl8_h + 6 * 16384; unsigned short* wr1a_l   = spl8_l + 6 * 16384;
    unsigned short* wr1b_h   = spl8_h + 7 * 16384; unsigned short* wr1b_l   = spl8_l + 7 * 16384;
    unsigned short* wu0_h = wu_h + 0;      unsigned short* wu0_l = wu_l + 0;
    unsigned short* wu1_h = wu_h + 32768;  unsigned short* wu1_l = wu_l + 32768;

    const int nbN = (NN + 63) / 64;
    const int nbE = (NE + 63) / 64;

    // ---- weight prep ----
    tsplit_pair_kernel<<<32, 256, 0, stream>>>(W_edge, 16, W_node, 32, wsm_h, wsm_l);
    {
        SrcList8 s8;
        s8.p[0] = Wm[0] + 128 * 128; s8.p[1] = Wm[1] + 128 * 128;
        s8.p[2] = Wm[0];             s8.p[3] = Wm[0] + 256 * 128;
        s8.p[4] = Wm[1];             s8.p[5] = Wm[1] + 256 * 128;
        s8.p[6] = W_r1;              s8.p[7] = W_r1 + 128 * 128;
        tsplit8_kernel<<<512, 256, 0, stream>>>(s8, spl8_h, spl8_l);
    }
    {
        SrcList2 s2;
        s2.p[0] = Wu[0]; s2.p[1] = Wu[1];
        tsplit2_kernel<<<256, 256, 0, stream>>>(s2, wu_h, wu_l);
    }

    // ---- sort edges by dst (scatter also permutes+splits edge feats) ----
    hipMemsetAsync(cnt, 0, NN * sizeof(int), stream);
    hist_kernel<<<(NE + 255) / 256, 256, 0, stream>>>(ei, cnt, NE);
    scan_kernel<<<1, 256, 0, stream>>>(cnt, fill, NN);
    scatter_kernel<<<(NE + 255) / 256, 256, 0, stream>>>(ei, edge_feats, fill,
                                                         ssrc, sdst, efh, efl, NE);

    // ---- encode + layer-0 projections ----
    encode_mfma_kernel<<<nbN, 256, 0, stream>>>(node_feats, wnT_h, wnT_l, b_node,
                                                wm0a_h, wm0a_l, wm0d_h, wm0d_l,
                                                B0, B1, B2, NN);
    // ---- layer 0 edge ----
    hipMemsetAsync(B3, 0, (size_t)NN * 128 * sizeof(float), stream);
    edge_msg_mfma_kernel<<<nbE, 512, 0, stream>>>(efh, efl, ssrc, sdst,
                                                  wehT_h, wehT_l, b_edge,
                                                  wm0mid_h, wm0mid_l, bm[0], B1, B2, B3, NE);
    // ---- update 0 + layer-1 projections (zeros B3 after reading it) ----
    update_mfma_kernel<<<nbN, 256, 0, stream>>>(B0, B3, wu0_h, wu0_l, bu[0],
                                                wm1a_h, wm1a_l, wm1d_h, wm1d_l,
                                                B0, B1, B2, NN);
    // ---- layer 1 edge (B3 already zeroed by update 0) ----
    edge_msg_mfma_kernel<<<nbE, 512, 0, stream>>>(efh, efl, ssrc, sdst,
                                                  wehT_h, wehT_l, b_edge,
                                                  wm1mid_h, wm1mid_l, bm[1], B1, B2, B3, NE);
    // ---- update 1 + readout projections ----
    update_mfma_kernel<<<nbN, 256, 0, stream>>>(B0, B3, wu1_h, wu1_l, bu[1],
                                                wr1a_h, wr1a_l, wr1b_h, wr1b_l,
                                                B0, B1, B2, NN);
    // ---- readout ----
    readout_kernel<<<2048, 256, 0, stream>>>(B1, B2, demand_feats, dp,
                                             W_r1 + 256 * 128, b_r1, W_r2, b_r2, out, ND);
}